// Round 4
// baseline (238.844 us; speedup 1.0000x reference)
//
#include <hip/hip_runtime.h>

#define DD 2048
#define HH 512
#define NTOK 16384

typedef __attribute__((ext_vector_type(8))) short short8_t;
typedef __attribute__((ext_vector_type(4))) short short4_t;
typedef __attribute__((ext_vector_type(4))) float f32x4;

static __device__ __forceinline__ short f2bf(float f) {
    union { float f; unsigned u; } v; v.f = f;
    unsigned r = (v.u + 0x7fffu + ((v.u >> 16) & 1u)) >> 16;
    return (short)r;
}

// async global->LDS, 16B/lane. dest base wave-uniform; HW adds lane*16.
static __device__ __forceinline__ void gl16(const short* g, short* l) {
    __builtin_amdgcn_global_load_lds(
        (const __attribute__((address_space(1))) unsigned int*)g,
        (__attribute__((address_space(3))) unsigned int*)l, 16, 0, 0);
}

// ---- prep: Wg = Wd*gamma bf16, c1=sum gamma*Wd, c2=sum beta*Wd; Wu -> bf16 ----
__global__ __launch_bounds__(256) void k_wprep(
    const float* __restrict__ Wd, const float* __restrict__ g,
    const float* __restrict__ be, const float* __restrict__ Wu,
    short* __restrict__ Wg, short* __restrict__ Wub,
    float* __restrict__ c1, float* __restrict__ c2)
{
    int bid = blockIdx.x;
    if (bid < 128) {
        int w = threadIdx.x >> 6, lane = threadIdx.x & 63;
        int h = bid * 4 + w;
        const float* wr = Wd + (size_t)h * DD;
        float s1 = 0.f, s2 = 0.f;
        for (int i = 0; i < 8; i++) {
            int col = i * 256 + lane * 4;
            float4 wv = *(const float4*)(wr + col);
            float4 gv = *(const float4*)(g + col);
            float4 bv = *(const float4*)(be + col);
            s1 += gv.x * wv.x + gv.y * wv.y + gv.z * wv.z + gv.w * wv.w;
            s2 += bv.x * wv.x + bv.y * wv.y + bv.z * wv.z + bv.w * wv.w;
            short4_t o;
            o[0] = f2bf(wv.x * gv.x); o[1] = f2bf(wv.y * gv.y);
            o[2] = f2bf(wv.z * gv.z); o[3] = f2bf(wv.w * gv.w);
            *(short4_t*)(Wg + (size_t)h * DD + col) = o;
        }
        for (int m = 1; m < 64; m <<= 1) { s1 += __shfl_xor(s1, m); s2 += __shfl_xor(s2, m); }
        if (lane == 0) { c1[h] = s1; c2[h] = s2; }
    } else {
        int b = bid - 128;  // 0..255
        for (int r = 0; r < 4; r++) {
            int i = (b * 4 + r) * 1024 + threadIdx.x * 4;
            float4 v = *(const float4*)(Wu + i);
            short4_t o;
            o[0] = f2bf(v.x); o[1] = f2bf(v.y); o[2] = f2bf(v.z); o[3] = f2bf(v.w);
            *(short4_t*)(Wub + i) = o;
        }
    }
}

// ---- k_down: hid = relu(LN-affine(x @ Wg^T)), tile 64m x 256n, BK=32 ----
__global__ __launch_bounds__(512, 4) void k_down(
    const float* __restrict__ x, const short* __restrict__ Wg,
    const float* __restrict__ c1, const float* __restrict__ c2,
    const float* __restrict__ bd, short* __restrict__ hid)
{
    __shared__ __align__(16) short sB[2][256 * 32];  // 32 KB
    __shared__ __align__(16) short sA[2][64 * 32];   // 8 KB
    __shared__ float s_ps[512], s_pq[512];           // 4 KB
    __shared__ float s_mu[64], s_rs[64];             // 512 B

    // bijective XCD swizzle (nwg=512), m-major pairs share x tile
    int bid = blockIdx.x;
    int nb = (bid & 7) * 64 + (bid >> 3);
    const int m0 = (nb >> 1) * 64;
    const int n0 = (nb & 1) * 256;

    const int tid = threadIdx.x, lane = tid & 63, w = tid >> 6;
    const int l15 = lane & 15, rg = lane >> 4;
    const int wm = w >> 2, wn = w & 3;        // 2x4 waves, 32m x 64n each
    const int arow = tid >> 3, ahalf = tid & 7;

    const float* xrow = x + (size_t)(m0 + arow) * DD + ahalf * 4;
    const int awoff = arow * 32 + (((ahalf >> 1) ^ (arow & 3)) << 3) + (ahalf & 1) * 4;

    float psum = 0.f, psq = 0.f;
    float4 xv;

    auto stageB = [&](int b, int kb) {
#pragma unroll
        for (int i = 0; i < 2; i++) {
            int ch = i * 512 + tid;
            int r = ch >> 2, c = ch & 3;
            gl16(Wg + (size_t)(n0 + r) * DD + kb + ((c ^ (r & 3)) << 3),
                 &sB[b][0] + (i * 512 + (w << 6)) * 8);
        }
    };
    auto loadA = [&](int kb) { xv = *(const float4*)(xrow + kb); };
    auto writeA = [&](int b) {
        psum += xv.x + xv.y + xv.z + xv.w;
        psq  += xv.x * xv.x + xv.y * xv.y + xv.z * xv.z + xv.w * xv.w;
        short4_t o;
        o[0] = f2bf(xv.x); o[1] = f2bf(xv.y); o[2] = f2bf(xv.z); o[3] = f2bf(xv.w);
        *(short4_t*)(&sA[b][0] + awoff) = o;
    };

    f32x4 acc[2][4];
#pragma unroll
    for (int i = 0; i < 2; i++)
#pragma unroll
        for (int j = 0; j < 4; j++) acc[i][j] = (f32x4){0.f, 0.f, 0.f, 0.f};

    stageB(0, 0);
    loadA(0);
    writeA(0);
    __syncthreads();

    for (int t = 0; t < 64; t++) {
        int cur = t & 1, nxt = cur ^ 1;
        if (t < 63) { stageB(nxt, (t + 1) * 32); loadA((t + 1) * 32); }
        short8_t af[2], bf[4];
#pragma unroll
        for (int mi = 0; mi < 2; mi++) {
            int rr = wm * 32 + mi * 16 + l15;
            af[mi] = *(const short8_t*)(&sA[cur][0] + rr * 32 + ((rg ^ (rr & 3)) << 3));
        }
#pragma unroll
        for (int ni = 0; ni < 4; ni++) {
            int rr = wn * 64 + ni * 16 + l15;
            bf[ni] = *(const short8_t*)(&sB[cur][0] + rr * 32 + ((rg ^ (rr & 3)) << 3));
        }
#pragma unroll
        for (int mi = 0; mi < 2; mi++)
#pragma unroll
            for (int ni = 0; ni < 4; ni++)
                acc[mi][ni] = __builtin_amdgcn_mfma_f32_16x16x32_bf16(
                    af[mi], bf[ni], acc[mi][ni], 0, 0, 0);
        if (t < 63) writeA(nxt);
        __syncthreads();
    }

    // LN stats reduce (8 partials per row)
    s_ps[tid] = psum;
    s_pq[tid] = psq;
    __syncthreads();
    if (tid < 64) {
        float s = 0.f, q = 0.f;
#pragma unroll
        for (int c = 0; c < 8; c++) { s += s_ps[tid * 8 + c]; q += s_pq[tid * 8 + c]; }
        float mu = s * (1.f / DD);
        float var = q * (1.f / DD) - mu * mu;
        s_mu[tid] = mu;
        s_rs[tid] = rsqrtf(var + 1e-5f);
    }
    __syncthreads();

    // epilogue: LN-affine + bias + relu -> hid (bf16, global)
#pragma unroll
    for (int ni = 0; ni < 4; ni++) {
        int h = n0 + wn * 64 + ni * 16 + l15;
        float C1 = c1[h];
        float C2 = c2[h] + bd[h];
#pragma unroll
        for (int mi = 0; mi < 2; mi++) {
#pragma unroll
            for (int j = 0; j < 4; j++) {
                int rowL = wm * 32 + mi * 16 + rg * 4 + j;
                float v = s_rs[rowL] * (acc[mi][ni][j] - s_mu[rowL] * C1) + C2;
                v = v > 0.f ? v : 0.f;
                hid[(size_t)(m0 + rowL) * HH + h] = f2bf(v);
            }
        }
    }
}

// ---- k_up: out = x + bu + hid @ Wu^T, tile 64m x 512n, BK=32 ----
__global__ __launch_bounds__(512, 4) void k_up(
    const float* __restrict__ x, const short* __restrict__ hid,
    const short* __restrict__ Wub, const float* __restrict__ bu,
    float* __restrict__ out)
{
    __shared__ __align__(16) short sB[2][512 * 32];  // 64 KB
    __shared__ __align__(16) short sA[2][64 * 32];   // 8 KB

    // bijective XCD swizzle (nwg=1024), n fastest so same-m blocks are adjacent
    int bid = blockIdx.x;
    int nb = (bid & 7) * 128 + (bid >> 3);
    const int n0 = (nb & 3) * 512;
    const int m0 = (nb >> 2) * 64;

    const int tid = threadIdx.x, lane = tid & 63, w = tid >> 6;
    const int l15 = lane & 15, rg = lane >> 4;

    auto stageB = [&](int b, int kb) {
#pragma unroll
        for (int i = 0; i < 4; i++) {
            int ch = i * 512 + tid;
            int r = ch >> 2, c = ch & 3;
            gl16(Wub + (size_t)(n0 + r) * HH + kb + ((c ^ (r & 3)) << 3),
                 &sB[b][0] + (i * 512 + (w << 6)) * 8);
        }
    };
    auto stageA = [&](int b, int kb) {
        if (w < 4) {
            int r = tid >> 2, c = tid & 3;  // 256 chunks = 64 rows x 4
            gl16(hid + (size_t)(m0 + r) * HH + kb + ((c ^ (r & 3)) << 3),
                 &sA[b][0] + (w << 6) * 8);
        }
    };

    f32x4 acc[4][4];
#pragma unroll
    for (int i = 0; i < 4; i++)
#pragma unroll
        for (int j = 0; j < 4; j++) acc[i][j] = (f32x4){0.f, 0.f, 0.f, 0.f};

    stageB(0, 0);
    stageA(0, 0);
    __syncthreads();

    for (int t = 0; t < 16; t++) {
        int cur = t & 1, nxt = cur ^ 1;
        if (t < 15) { stageB(nxt, (t + 1) * 32); stageA(nxt, (t + 1) * 32); }
        short8_t af[4], bf[4];
#pragma unroll
        for (int mi = 0; mi < 4; mi++) {
            int rr = mi * 16 + l15;
            af[mi] = *(const short8_t*)(&sA[cur][0] + rr * 32 + ((rg ^ (rr & 3)) << 3));
        }
#pragma unroll
        for (int ni = 0; ni < 4; ni++) {
            int rr = (w << 6) + ni * 16 + l15;
            bf[ni] = *(const short8_t*)(&sB[cur][0] + rr * 32 + ((rg ^ (rr & 3)) << 3));
        }
#pragma unroll
        for (int mi = 0; mi < 4; mi++)
#pragma unroll
            for (int ni = 0; ni < 4; ni++)
                acc[mi][ni] = __builtin_amdgcn_mfma_f32_16x16x32_bf16(
                    af[mi], bf[ni], acc[mi][ni], 0, 0, 0);
        __syncthreads();
    }

    // epilogue: out = x + bu + acc
#pragma unroll
    for (int ni = 0; ni < 4; ni++) {
        int d = n0 + (w << 6) + ni * 16 + l15;
        float B = bu[d];
#pragma unroll
        for (int mi = 0; mi < 4; mi++) {
#pragma unroll
            for (int j = 0; j < 4; j++) {
                int rowL = mi * 16 + rg * 4 + j;
                size_t idx = (size_t)(m0 + rowL) * DD + d;
                out[idx] = x[idx] + B + acc[mi][ni][j];
            }
        }
    }
}

extern "C" void kernel_launch(void* const* d_in, const int* in_sizes, int n_in,
                              void* d_out, int out_size, void* d_ws, size_t ws_size,
                              hipStream_t stream) {
    const float* x     = (const float*)d_in[0];
    const float* gamma = (const float*)d_in[1];
    const float* beta  = (const float*)d_in[2];
    const float* Wd_f  = (const float*)d_in[3];  // [H, D]
    const float* bd    = (const float*)d_in[4];
    const float* Wu_f  = (const float*)d_in[5];  // [D, H]
    const float* bu    = (const float*)d_in[6];

    short* Wg  = (short*)d_ws;                     // 2 MB bf16 [H][D] (Wd*gamma)
    short* Wub = Wg + (size_t)HH * DD;             // 2 MB bf16 [D][H]
    float* c1  = (float*)(Wub + (size_t)DD * HH);  // 2 KB
    float* c2  = c1 + HH;                          // 2 KB
    short* hid = (short*)(c2 + HH);                // 16 MB bf16 [NTOK][H]

    k_wprep<<<384, 256, 0, stream>>>(Wd_f, gamma, beta, Wu_f, Wg, Wub, c1, c2);
    k_down<<<(NTOK / 64) * (HH / 256), 512, 0, stream>>>(x, Wg, c1, c2, bd, hid);
    k_up<<<(NTOK / 64) * (DD / 512), 512, 0, stream>>>(x, hid, Wub, bu, (float*)d_out);
}

// Round 5
// 158.135 us; speedup vs baseline: 1.5104x; 1.5104x over previous
//
#include <hip/hip_runtime.h>

#define DD 2048
#define HH 512
#define NTOK 16384

typedef __attribute__((ext_vector_type(8))) short short8_t;
typedef __attribute__((ext_vector_type(4))) short short4_t;
typedef __attribute__((ext_vector_type(4))) float f32x4;

static __device__ __forceinline__ short f2bf(float f) {
    union { float f; unsigned u; } v; v.f = f;
    unsigned r = (v.u + 0x7fffu + ((v.u >> 16) & 1u)) >> 16;
    return (short)r;
}

// async global->LDS, 16B/lane. dest base wave-uniform; HW adds lane*16.
static __device__ __forceinline__ void gl16(const short* g, short* l) {
    __builtin_amdgcn_global_load_lds(
        (const __attribute__((address_space(1))) unsigned int*)g,
        (__attribute__((address_space(3))) unsigned int*)l, 16, 0, 0);
}

// ---- prep: Wg = Wd*gamma bf16, c1=sum gamma*Wd, c2=sum beta*Wd; Wu -> bf16 ----
__global__ __launch_bounds__(256) void k_wprep(
    const float* __restrict__ Wd, const float* __restrict__ g,
    const float* __restrict__ be, const float* __restrict__ Wu,
    short* __restrict__ Wg, short* __restrict__ Wub,
    float* __restrict__ c1, float* __restrict__ c2)
{
    int bid = blockIdx.x;
    if (bid < 128) {
        int w = threadIdx.x >> 6, lane = threadIdx.x & 63;
        int h = bid * 4 + w;
        const float* wr = Wd + (size_t)h * DD;
        float s1 = 0.f, s2 = 0.f;
        for (int i = 0; i < 8; i++) {
            int col = i * 256 + lane * 4;
            float4 wv = *(const float4*)(wr + col);
            float4 gv = *(const float4*)(g + col);
            float4 bv = *(const float4*)(be + col);
            s1 += gv.x * wv.x + gv.y * wv.y + gv.z * wv.z + gv.w * wv.w;
            s2 += bv.x * wv.x + bv.y * wv.y + bv.z * wv.z + bv.w * wv.w;
            short4_t o;
            o[0] = f2bf(wv.x * gv.x); o[1] = f2bf(wv.y * gv.y);
            o[2] = f2bf(wv.z * gv.z); o[3] = f2bf(wv.w * gv.w);
            *(short4_t*)(Wg + (size_t)h * DD + col) = o;
        }
        for (int m = 1; m < 64; m <<= 1) { s1 += __shfl_xor(s1, m); s2 += __shfl_xor(s2, m); }
        if (lane == 0) { c1[h] = s1; c2[h] = s2; }
    } else {
        int b = bid - 128;  // 0..255
        for (int r = 0; r < 4; r++) {
            int i = (b * 4 + r) * 1024 + threadIdx.x * 4;
            float4 v = *(const float4*)(Wu + i);
            short4_t o;
            o[0] = f2bf(v.x); o[1] = f2bf(v.y); o[2] = f2bf(v.z); o[3] = f2bf(v.w);
            *(short4_t*)(Wub + i) = o;
        }
    }
}

// ---- k_down: hid = relu(LN-affine(x @ Wg^T)), 128x128 tile, BK=64, dbuf ----
__global__ __launch_bounds__(256, 2) void k_down(
    const float* __restrict__ x, const short* __restrict__ Wg,
    const float* __restrict__ c1, const float* __restrict__ c2,
    const float* __restrict__ bd, short* __restrict__ hid)
{
    __shared__ __align__(16) short sA[2][128 * 64];  // 32 KB
    __shared__ __align__(16) short sB[2][128 * 64];  // 32 KB
    __shared__ float s_ps[128][8], s_pq[128][8];     // 8 KB
    __shared__ float s_mu[128], s_rs[128];           // 1 KB

    // bijective XCD swizzle (nwg=512), n fastest within each XCD chunk
    int bid = blockIdx.x;
    int nb = (bid & 7) * 64 + (bid >> 3);
    const int m0 = (nb >> 2) * 128;
    const int n0 = (nb & 3) * 128;

    const int tid = threadIdx.x, lane = tid & 63, w = tid >> 6;
    const int l15 = lane & 15, rg = lane >> 4;
    const int wm = w >> 1, wn = w & 1;   // 2x2 waves, 64x64 each
    const int sr = tid >> 3, sc = tid & 7;   // A-stage: rows sr+32i, 8-float chunk sc

    const float* xrow = x + (size_t)m0 * DD + (size_t)sr * DD + sc * 8;

    auto stageB = [&](int b, int kb) {
#pragma unroll
        for (int i = 0; i < 4; i++) {
            int ch = i * 256 + tid;
            int r = ch >> 3, c = ch & 7;
            gl16(Wg + (size_t)(n0 + r) * DD + kb + ((c ^ (r & 7)) << 3),
                 &sB[b][0] + (i * 256 + (w << 6)) * 8);
        }
    };

    float4 xv[4][2];
    auto loadA = [&](int kb) {
#pragma unroll
        for (int i = 0; i < 4; i++) {
            const float* p = xrow + (size_t)(i * 32) * DD + kb;
            xv[i][0] = *(const float4*)p;
            xv[i][1] = *(const float4*)(p + 4);
        }
    };
    float psum[4] = {0.f, 0.f, 0.f, 0.f}, psq[4] = {0.f, 0.f, 0.f, 0.f};
    auto writeA = [&](int b) {
#pragma unroll
        for (int i = 0; i < 4; i++) {
            float4 v0 = xv[i][0], v1 = xv[i][1];
            psum[i] += v0.x + v0.y + v0.z + v0.w + v1.x + v1.y + v1.z + v1.w;
            psq[i]  += v0.x * v0.x + v0.y * v0.y + v0.z * v0.z + v0.w * v0.w
                     + v1.x * v1.x + v1.y * v1.y + v1.z * v1.z + v1.w * v1.w;
            short8_t o;
            o[0] = f2bf(v0.x); o[1] = f2bf(v0.y); o[2] = f2bf(v0.z); o[3] = f2bf(v0.w);
            o[4] = f2bf(v1.x); o[5] = f2bf(v1.y); o[6] = f2bf(v1.z); o[7] = f2bf(v1.w);
            int r = i * 32 + sr;
            *(short8_t*)(&sA[b][0] + r * 64 + ((sc ^ (r & 7)) << 3)) = o;
        }
    };

    f32x4 acc[4][4];
#pragma unroll
    for (int i = 0; i < 4; i++)
#pragma unroll
        for (int j = 0; j < 4; j++) acc[i][j] = (f32x4){0.f, 0.f, 0.f, 0.f};

    stageB(0, 0);
    loadA(0);
    writeA(0);
    __syncthreads();

    for (int t = 0; t < 32; t++) {
        int cur = t & 1, nxt = cur ^ 1;
        if (t < 31) { stageB(nxt, (t + 1) * 64); loadA((t + 1) * 64); }
#pragma unroll
        for (int kk = 0; kk < 2; kk++) {
            int kc = kk * 4 + rg;
            short8_t af[4], bf[4];
#pragma unroll
            for (int mi = 0; mi < 4; mi++) {
                int rr = wm * 64 + mi * 16 + l15;
                af[mi] = *(const short8_t*)(&sA[cur][0] + rr * 64 + ((kc ^ (rr & 7)) << 3));
            }
#pragma unroll
            for (int ni = 0; ni < 4; ni++) {
                int rr = wn * 64 + ni * 16 + l15;
                bf[ni] = *(const short8_t*)(&sB[cur][0] + rr * 64 + ((kc ^ (rr & 7)) << 3));
            }
#pragma unroll
            for (int mi = 0; mi < 4; mi++)
#pragma unroll
                for (int ni = 0; ni < 4; ni++)
                    acc[mi][ni] = __builtin_amdgcn_mfma_f32_16x16x32_bf16(
                        af[mi], bf[ni], acc[mi][ni], 0, 0, 0);
        }
        if (t < 31) writeA(nxt);
        __syncthreads();
    }

    // LN stats reduce (8 partials per row)
#pragma unroll
    for (int i = 0; i < 4; i++) {
        s_ps[i * 32 + sr][sc] = psum[i];
        s_pq[i * 32 + sr][sc] = psq[i];
    }
    __syncthreads();
    if (tid < 128) {
        float s = 0.f, q = 0.f;
#pragma unroll
        for (int c = 0; c < 8; c++) { s += s_ps[tid][c]; q += s_pq[tid][c]; }
        float mu = s * (1.f / DD);
        float var = q * (1.f / DD) - mu * mu;
        s_mu[tid] = mu;
        s_rs[tid] = rsqrtf(var + 1e-5f);
    }
    __syncthreads();

    // epilogue: LN-affine + bias + relu -> hid (bf16)
#pragma unroll
    for (int ni = 0; ni < 4; ni++) {
        int h = n0 + wn * 64 + ni * 16 + l15;
        float C1 = c1[h];
        float C2 = c2[h] + bd[h];
#pragma unroll
        for (int mi = 0; mi < 4; mi++) {
#pragma unroll
            for (int j = 0; j < 4; j++) {
                int rowL = wm * 64 + mi * 16 + rg * 4 + j;
                float v = s_rs[rowL] * (acc[mi][ni][j] - s_mu[rowL] * C1) + C2;
                v = v > 0.f ? v : 0.f;
                hid[(size_t)(m0 + rowL) * HH + h] = f2bf(v);
            }
        }
    }
}

// ---- k_up: out = x + bu + hid @ Wu^T, 128x128 tile, BK=64, dbuf ----
__global__ __launch_bounds__(256, 2) void k_up(
    const float* __restrict__ x, const short* __restrict__ hid,
    const short* __restrict__ Wub, const float* __restrict__ bu,
    float* __restrict__ out)
{
    __shared__ __align__(16) short sA[2][128 * 64];  // 32 KB
    __shared__ __align__(16) short sB[2][128 * 64];  // 32 KB

    // bijective XCD swizzle (nwg=2048), n fastest within each XCD chunk
    int bid = blockIdx.x;
    int nb = (bid & 7) * 256 + (bid >> 3);
    const int m0 = (nb >> 4) * 128;
    const int n0 = (nb & 15) * 128;

    const int tid = threadIdx.x, lane = tid & 63, w = tid >> 6;
    const int l15 = lane & 15, rg = lane >> 4;
    const int wm = w >> 1, wn = w & 1;

    auto stage = [&](int b, int kb) {
#pragma unroll
        for (int i = 0; i < 4; i++) {
            int ch = i * 256 + tid;
            int r = ch >> 3, c = ch & 7;
            int co = ((c ^ (r & 7)) << 3);
            gl16(hid + (size_t)(m0 + r) * HH + kb + co,
                 &sA[b][0] + (i * 256 + (w << 6)) * 8);
            gl16(Wub + (size_t)(n0 + r) * HH + kb + co,
                 &sB[b][0] + (i * 256 + (w << 6)) * 8);
        }
    };

    f32x4 acc[4][4];
#pragma unroll
    for (int i = 0; i < 4; i++)
#pragma unroll
        for (int j = 0; j < 4; j++) acc[i][j] = (f32x4){0.f, 0.f, 0.f, 0.f};

    stage(0, 0);
    __syncthreads();

    for (int t = 0; t < 8; t++) {
        int cur = t & 1, nxt = cur ^ 1;
        if (t < 7) stage(nxt, (t + 1) * 64);
#pragma unroll
        for (int kk = 0; kk < 2; kk++) {
            int kc = kk * 4 + rg;
            short8_t af[4], bf[4];
#pragma unroll
            for (int mi = 0; mi < 4; mi++) {
                int rr = wm * 64 + mi * 16 + l15;
                af[mi] = *(const short8_t*)(&sA[cur][0] + rr * 64 + ((kc ^ (rr & 7)) << 3));
            }
#pragma unroll
            for (int ni = 0; ni < 4; ni++) {
                int rr = wn * 64 + ni * 16 + l15;
                bf[ni] = *(const short8_t*)(&sB[cur][0] + rr * 64 + ((kc ^ (rr & 7)) << 3));
            }
#pragma unroll
            for (int mi = 0; mi < 4; mi++)
#pragma unroll
                for (int ni = 0; ni < 4; ni++)
                    acc[mi][ni] = __builtin_amdgcn_mfma_f32_16x16x32_bf16(
                        af[mi], bf[ni], acc[mi][ni], 0, 0, 0);
        }
        __syncthreads();
    }

    // epilogue: out = x + bu + acc
#pragma unroll
    for (int ni = 0; ni < 4; ni++) {
        int d = n0 + wn * 64 + ni * 16 + l15;
        float B = bu[d];
#pragma unroll
        for (int mi = 0; mi < 4; mi++) {
#pragma unroll
            for (int j = 0; j < 4; j++) {
                int rowL = wm * 64 + mi * 16 + rg * 4 + j;
                size_t idx = (size_t)(m0 + rowL) * DD + d;
                out[idx] = x[idx] + B + acc[mi][ni][j];
            }
        }
    }
}

extern "C" void kernel_launch(void* const* d_in, const int* in_sizes, int n_in,
                              void* d_out, int out_size, void* d_ws, size_t ws_size,
                              hipStream_t stream) {
    const float* x     = (const float*)d_in[0];
    const float* gamma = (const float*)d_in[1];
    const float* beta  = (const float*)d_in[2];
    const float* Wd_f  = (const float*)d_in[3];  // [H, D]
    const float* bd    = (const float*)d_in[4];
    const float* Wu_f  = (const float*)d_in[5];  // [D, H]
    const float* bu    = (const float*)d_in[6];

    short* Wg  = (short*)d_ws;                     // 2 MB bf16 [H][D] (Wd*gamma)
    short* Wub = Wg + (size_t)HH * DD;             // 2 MB bf16 [D][H]
    float* c1  = (float*)(Wub + (size_t)DD * HH);  // 2 KB
    float* c2  = c1 + HH;                          // 2 KB
    short* hid = (short*)(c2 + HH);                // 16 MB bf16 [NTOK][H]

    k_wprep<<<384, 256, 0, stream>>>(Wd_f, gamma, beta, Wu_f, Wg, Wub, c1, c2);
    k_down<<<(NTOK / 128) * (HH / 128), 256, 0, stream>>>(x, Wg, c1, c2, bd, hid);
    k_up<<<(NTOK / 128) * (DD / 128), 256, 0, stream>>>(x, hid, Wub, bu, (float*)d_out);
}

// Round 6
// 155.889 us; speedup vs baseline: 1.5321x; 1.0144x over previous
//
#include <hip/hip_runtime.h>

#define DD 2048
#define HH 512
#define NTOK 16384

typedef __attribute__((ext_vector_type(8))) short short8_t;
typedef __attribute__((ext_vector_type(4))) short short4_t;
typedef __attribute__((ext_vector_type(4))) float f32x4;

static __device__ __forceinline__ short f2bf(float f) {
    union { float f; unsigned u; } v; v.f = f;
    unsigned r = (v.u + 0x7fffu + ((v.u >> 16) & 1u)) >> 16;
    return (short)r;
}

// async global->LDS, 16B/lane. dest base wave-uniform; HW adds lane*16.
static __device__ __forceinline__ void gl16(const short* g, short* l) {
    __builtin_amdgcn_global_load_lds(
        (const __attribute__((address_space(1))) unsigned int*)g,
        (__attribute__((address_space(3))) unsigned int*)l, 16, 0, 0);
}

// ---- prep: blocks 0..127 Wg=Wd*gamma + c2; 128..383 Wu->bf16;
//            384..16767: LN-normalize one token row -> xn bf16 ----
__global__ __launch_bounds__(256) void k_prep(
    const float* __restrict__ Wd, const float* __restrict__ g,
    const float* __restrict__ be, const float* __restrict__ Wu,
    const float* __restrict__ x,
    short* __restrict__ Wg, short* __restrict__ Wub,
    float* __restrict__ c2, short* __restrict__ xn)
{
    __shared__ float ss[4], sq[4];
    int bid = blockIdx.x;
    int w = threadIdx.x >> 6, lane = threadIdx.x & 63;
    if (bid < 128) {
        int h = bid * 4 + w;
        const float* wr = Wd + (size_t)h * DD;
        float s2 = 0.f;
        for (int i = 0; i < 8; i++) {
            int col = i * 256 + lane * 4;
            float4 wv = *(const float4*)(wr + col);
            float4 gv = *(const float4*)(g + col);
            float4 bv = *(const float4*)(be + col);
            s2 += bv.x * wv.x + bv.y * wv.y + bv.z * wv.z + bv.w * wv.w;
            short4_t o;
            o[0] = f2bf(wv.x * gv.x); o[1] = f2bf(wv.y * gv.y);
            o[2] = f2bf(wv.z * gv.z); o[3] = f2bf(wv.w * gv.w);
            *(short4_t*)(Wg + (size_t)h * DD + col) = o;
        }
        for (int m = 1; m < 64; m <<= 1) s2 += __shfl_xor(s2, m);
        if (lane == 0) c2[h] = s2;
    } else if (bid < 384) {
        int b = bid - 128;  // 0..255
        for (int r = 0; r < 4; r++) {
            int i = (b * 4 + r) * 1024 + threadIdx.x * 4;
            float4 v = *(const float4*)(Wu + i);
            short4_t o;
            o[0] = f2bf(v.x); o[1] = f2bf(v.y); o[2] = f2bf(v.z); o[3] = f2bf(v.w);
            *(short4_t*)(Wub + i) = o;
        }
    } else {
        int row = bid - 384;
        const float* xr = x + (size_t)row * DD + threadIdx.x * 8;
        float4 a = *(const float4*)xr;
        float4 b = *(const float4*)(xr + 4);
        float s = a.x + a.y + a.z + a.w + b.x + b.y + b.z + b.w;
        float q = a.x * a.x + a.y * a.y + a.z * a.z + a.w * a.w
                + b.x * b.x + b.y * b.y + b.z * b.z + b.w * b.w;
        for (int m = 1; m < 64; m <<= 1) { s += __shfl_xor(s, m); q += __shfl_xor(q, m); }
        if (lane == 0) { ss[w] = s; sq[w] = q; }
        __syncthreads();
        float S = ss[0] + ss[1] + ss[2] + ss[3];
        float Q = sq[0] + sq[1] + sq[2] + sq[3];
        float mu = S * (1.f / DD);
        float rs = rsqrtf(Q * (1.f / DD) - mu * mu + 1e-5f);
        short8_t o;
        o[0] = f2bf((a.x - mu) * rs); o[1] = f2bf((a.y - mu) * rs);
        o[2] = f2bf((a.z - mu) * rs); o[3] = f2bf((a.w - mu) * rs);
        o[4] = f2bf((b.x - mu) * rs); o[5] = f2bf((b.y - mu) * rs);
        o[6] = f2bf((b.z - mu) * rs); o[7] = f2bf((b.w - mu) * rs);
        *(short8_t*)(xn + (size_t)row * DD + threadIdx.x * 8) = o;
    }
}

// ---- k_down: hid = relu(xn @ Wg^T + c2 + bd), 128x128 tile, BK=64, dbuf ----
__global__ __launch_bounds__(256, 2) void k_down(
    const short* __restrict__ xn, const short* __restrict__ Wg,
    const float* __restrict__ c2, const float* __restrict__ bd,
    short* __restrict__ hid)
{
    __shared__ __align__(16) short sA[2][128 * 64];  // 32 KB
    __shared__ __align__(16) short sB[2][128 * 64];  // 32 KB

    // bijective XCD swizzle (nwg=512), n fastest within each XCD chunk
    int bid = blockIdx.x;
    int nb = (bid & 7) * 64 + (bid >> 3);
    const int m0 = (nb >> 2) * 128;
    const int n0 = (nb & 3) * 128;

    const int tid = threadIdx.x, lane = tid & 63, w = tid >> 6;
    const int l15 = lane & 15, rg = lane >> 4;
    const int wm = w >> 1, wn = w & 1;

    auto stage = [&](int b, int kb) {
#pragma unroll
        for (int i = 0; i < 4; i++) {
            int ch = i * 256 + tid;
            int r = ch >> 3, c = ch & 7;
            int co = ((c ^ (r & 7)) << 3);
            gl16(xn + (size_t)(m0 + r) * DD + kb + co,
                 &sA[b][0] + (i * 256 + (w << 6)) * 8);
            gl16(Wg + (size_t)(n0 + r) * DD + kb + co,
                 &sB[b][0] + (i * 256 + (w << 6)) * 8);
        }
    };

    f32x4 acc[4][4];
#pragma unroll
    for (int i = 0; i < 4; i++)
#pragma unroll
        for (int j = 0; j < 4; j++) acc[i][j] = (f32x4){0.f, 0.f, 0.f, 0.f};

    stage(0, 0);
    __syncthreads();

    for (int t = 0; t < 32; t++) {
        int cur = t & 1, nxt = cur ^ 1;
        if (t < 31) stage(nxt, (t + 1) * 64);
#pragma unroll
        for (int kk = 0; kk < 2; kk++) {
            int kc = kk * 4 + rg;
            short8_t af[4], bf[4];
#pragma unroll
            for (int mi = 0; mi < 4; mi++) {
                int rr = wm * 64 + mi * 16 + l15;
                af[mi] = *(const short8_t*)(&sA[cur][0] + rr * 64 + ((kc ^ (rr & 7)) << 3));
            }
#pragma unroll
            for (int ni = 0; ni < 4; ni++) {
                int rr = wn * 64 + ni * 16 + l15;
                bf[ni] = *(const short8_t*)(&sB[cur][0] + rr * 64 + ((kc ^ (rr & 7)) << 3));
            }
#pragma unroll
            for (int mi = 0; mi < 4; mi++)
#pragma unroll
                for (int ni = 0; ni < 4; ni++)
                    acc[mi][ni] = __builtin_amdgcn_mfma_f32_16x16x32_bf16(
                        af[mi], bf[ni], acc[mi][ni], 0, 0, 0);
        }
        __syncthreads();
    }

    // epilogue: + c2 + bd, relu -> hid bf16
#pragma unroll
    for (int ni = 0; ni < 4; ni++) {
        int h = n0 + wn * 64 + ni * 16 + l15;
        float C = c2[h] + bd[h];
#pragma unroll
        for (int mi = 0; mi < 4; mi++) {
#pragma unroll
            for (int j = 0; j < 4; j++) {
                int rowL = wm * 64 + mi * 16 + rg * 4 + j;
                float v = acc[mi][ni][j] + C;
                v = v > 0.f ? v : 0.f;
                hid[(size_t)(m0 + rowL) * HH + h] = f2bf(v);
            }
        }
    }
}

// ---- k_up: out = x + bu + hid @ Wu^T, 128x128 tile, BK=64, dbuf ----
__global__ __launch_bounds__(256, 2) void k_up(
    const float* __restrict__ x, const short* __restrict__ hid,
    const short* __restrict__ Wub, const float* __restrict__ bu,
    float* __restrict__ out)
{
    __shared__ __align__(16) short sA[2][128 * 64];  // 32 KB
    __shared__ __align__(16) short sB[2][128 * 64];  // 32 KB

    // bijective XCD swizzle (nwg=2048), n fastest within each XCD chunk
    int bid = blockIdx.x;
    int nb = (bid & 7) * 256 + (bid >> 3);
    const int m0 = (nb >> 4) * 128;
    const int n0 = (nb & 15) * 128;

    const int tid = threadIdx.x, lane = tid & 63, w = tid >> 6;
    const int l15 = lane & 15, rg = lane >> 4;
    const int wm = w >> 1, wn = w & 1;

    auto stage = [&](int b, int kb) {
#pragma unroll
        for (int i = 0; i < 4; i++) {
            int ch = i * 256 + tid;
            int r = ch >> 3, c = ch & 7;
            int co = ((c ^ (r & 7)) << 3);
            gl16(hid + (size_t)(m0 + r) * HH + kb + co,
                 &sA[b][0] + (i * 256 + (w << 6)) * 8);
            gl16(Wub + (size_t)(n0 + r) * HH + kb + co,
                 &sB[b][0] + (i * 256 + (w << 6)) * 8);
        }
    };

    f32x4 acc[4][4];
#pragma unroll
    for (int i = 0; i < 4; i++)
#pragma unroll
        for (int j = 0; j < 4; j++) acc[i][j] = (f32x4){0.f, 0.f, 0.f, 0.f};

    stage(0, 0);
    __syncthreads();

    for (int t = 0; t < 8; t++) {
        int cur = t & 1, nxt = cur ^ 1;
        if (t < 7) stage(nxt, (t + 1) * 64);
#pragma unroll
        for (int kk = 0; kk < 2; kk++) {
            int kc = kk * 4 + rg;
            short8_t af[4], bf[4];
#pragma unroll
            for (int mi = 0; mi < 4; mi++) {
                int rr = wm * 64 + mi * 16 + l15;
                af[mi] = *(const short8_t*)(&sA[cur][0] + rr * 64 + ((kc ^ (rr & 7)) << 3));
            }
#pragma unroll
            for (int ni = 0; ni < 4; ni++) {
                int rr = wn * 64 + ni * 16 + l15;
                bf[ni] = *(const short8_t*)(&sB[cur][0] + rr * 64 + ((kc ^ (rr & 7)) << 3));
            }
#pragma unroll
            for (int mi = 0; mi < 4; mi++)
#pragma unroll
                for (int ni = 0; ni < 4; ni++)
                    acc[mi][ni] = __builtin_amdgcn_mfma_f32_16x16x32_bf16(
                        af[mi], bf[ni], acc[mi][ni], 0, 0, 0);
        }
        __syncthreads();
    }

    // epilogue: out = x + bu + acc
#pragma unroll
    for (int ni = 0; ni < 4; ni++) {
        int d = n0 + wn * 64 + ni * 16 + l15;
        float B = bu[d];
#pragma unroll
        for (int mi = 0; mi < 4; mi++) {
#pragma unroll
            for (int j = 0; j < 4; j++) {
                int rowL = wm * 64 + mi * 16 + rg * 4 + j;
                size_t idx = (size_t)(m0 + rowL) * DD + d;
                out[idx] = x[idx] + B + acc[mi][ni][j];
            }
        }
    }
}

extern "C" void kernel_launch(void* const* d_in, const int* in_sizes, int n_in,
                              void* d_out, int out_size, void* d_ws, size_t ws_size,
                              hipStream_t stream) {
    const float* x     = (const float*)d_in[0];
    const float* gamma = (const float*)d_in[1];
    const float* beta  = (const float*)d_in[2];
    const float* Wd_f  = (const float*)d_in[3];  // [H, D]
    const float* bd    = (const float*)d_in[4];
    const float* Wu_f  = (const float*)d_in[5];  // [D, H]
    const float* bu    = (const float*)d_in[6];

    short* Wg  = (short*)d_ws;                     // 2 MB bf16 [H][D] (Wd*gamma)
    short* Wub = Wg + (size_t)HH * DD;             // 2 MB bf16 [D][H]
    float* c2  = (float*)(Wub + (size_t)DD * HH);  // 2 KB
    short* hid = (short*)(c2 + HH);                // 16 MB bf16 [NTOK][H]
    short* xn  = hid + (size_t)NTOK * HH;          // 64 MB bf16 [NTOK][D]

    k_prep<<<384 + NTOK, 256, 0, stream>>>(Wd_f, gamma, beta, Wu_f, x, Wg, Wub, c2, xn);
    k_down<<<(NTOK / 128) * (HH / 128), 256, 0, stream>>>(xn, Wg, c2, bd, hid);
    k_up<<<(NTOK / 128) * (DD / 128), 256, 0, stream>>>(x, hid, Wub, bu, (float*)d_out);
}

// Round 7
// 154.656 us; speedup vs baseline: 1.5444x; 1.0080x over previous
//
#include <hip/hip_runtime.h>

#define DD 2048
#define HH 512
#define NTOK 16384

typedef __attribute__((ext_vector_type(8))) short short8_t;
typedef __attribute__((ext_vector_type(4))) short short4_t;
typedef __attribute__((ext_vector_type(4))) float f32x4;

static __device__ __forceinline__ short f2bf(float f) {
    union { float f; unsigned u; } v; v.f = f;
    unsigned r = (v.u + 0x7fffu + ((v.u >> 16) & 1u)) >> 16;
    return (short)r;
}
static __device__ __forceinline__ float bf2f(unsigned short s) {
    union { unsigned u; float f; } v; v.u = (unsigned)s << 16;
    return v.f;
}

// async global->LDS, 16B/lane. dest base wave-uniform; HW adds lane*16.
static __device__ __forceinline__ void gl16(const short* g, short* l) {
    __builtin_amdgcn_global_load_lds(
        (const __attribute__((address_space(1))) unsigned int*)g,
        (__attribute__((address_space(3))) unsigned int*)l, 16, 0, 0);
}

// ---- prep: blocks 0..127 Wg=Wd*gamma + c2; 128..383 Wu->bf16;
//            384..16767: LN-normalize one token row -> xn bf16, save mu/sd ----
__global__ __launch_bounds__(256) void k_prep(
    const float* __restrict__ Wd, const float* __restrict__ g,
    const float* __restrict__ be, const float* __restrict__ Wu,
    const float* __restrict__ x,
    short* __restrict__ Wg, short* __restrict__ Wub,
    float* __restrict__ c2, short* __restrict__ xn,
    float* __restrict__ muv, float* __restrict__ sdv)
{
    __shared__ float ss[4], sq[4];
    int bid = blockIdx.x;
    int w = threadIdx.x >> 6, lane = threadIdx.x & 63;
    if (bid < 128) {
        int h = bid * 4 + w;
        const float* wr = Wd + (size_t)h * DD;
        float s2 = 0.f;
        for (int i = 0; i < 8; i++) {
            int col = i * 256 + lane * 4;
            float4 wv = *(const float4*)(wr + col);
            float4 gv = *(const float4*)(g + col);
            float4 bv = *(const float4*)(be + col);
            s2 += bv.x * wv.x + bv.y * wv.y + bv.z * wv.z + bv.w * wv.w;
            short4_t o;
            o[0] = f2bf(wv.x * gv.x); o[1] = f2bf(wv.y * gv.y);
            o[2] = f2bf(wv.z * gv.z); o[3] = f2bf(wv.w * gv.w);
            *(short4_t*)(Wg + (size_t)h * DD + col) = o;
        }
        for (int m = 1; m < 64; m <<= 1) s2 += __shfl_xor(s2, m);
        if (lane == 0) c2[h] = s2;
    } else if (bid < 384) {
        int b = bid - 128;  // 0..255
        for (int r = 0; r < 4; r++) {
            int i = (b * 4 + r) * 1024 + threadIdx.x * 4;
            float4 v = *(const float4*)(Wu + i);
            short4_t o;
            o[0] = f2bf(v.x); o[1] = f2bf(v.y); o[2] = f2bf(v.z); o[3] = f2bf(v.w);
            *(short4_t*)(Wub + i) = o;
        }
    } else {
        int row = bid - 384;
        const float* xr = x + (size_t)row * DD + threadIdx.x * 8;
        float4 a = *(const float4*)xr;
        float4 b = *(const float4*)(xr + 4);
        float s = a.x + a.y + a.z + a.w + b.x + b.y + b.z + b.w;
        float q = a.x * a.x + a.y * a.y + a.z * a.z + a.w * a.w
                + b.x * b.x + b.y * b.y + b.z * b.z + b.w * b.w;
        for (int m = 1; m < 64; m <<= 1) { s += __shfl_xor(s, m); q += __shfl_xor(q, m); }
        if (lane == 0) { ss[w] = s; sq[w] = q; }
        __syncthreads();
        float S = ss[0] + ss[1] + ss[2] + ss[3];
        float Q = sq[0] + sq[1] + sq[2] + sq[3];
        float mu = S * (1.f / DD);
        float ve = Q * (1.f / DD) - mu * mu + 1e-5f;
        float rs = rsqrtf(ve);
        if (threadIdx.x == 0) { muv[row] = mu; sdv[row] = ve * rs; }
        short8_t o;
        o[0] = f2bf((a.x - mu) * rs); o[1] = f2bf((a.y - mu) * rs);
        o[2] = f2bf((a.z - mu) * rs); o[3] = f2bf((a.w - mu) * rs);
        o[4] = f2bf((b.x - mu) * rs); o[5] = f2bf((b.y - mu) * rs);
        o[6] = f2bf((b.z - mu) * rs); o[7] = f2bf((b.w - mu) * rs);
        *(short8_t*)(xn + (size_t)row * DD + threadIdx.x * 8) = o;
    }
}

// ---- k_down: hid = relu(xn @ Wg^T + c2 + bd), 128x128 tile, BK=64, dbuf ----
__global__ __launch_bounds__(256, 2) void k_down(
    const short* __restrict__ xn, const short* __restrict__ Wg,
    const float* __restrict__ c2, const float* __restrict__ bd,
    short* __restrict__ hid)
{
    __shared__ __align__(16) short sA[2][128 * 64];  // 32 KB
    __shared__ __align__(16) short sB[2][128 * 64];  // 32 KB

    // bijective XCD swizzle (nwg=512), n fastest within each XCD chunk
    int bid = blockIdx.x;
    int nb = (bid & 7) * 64 + (bid >> 3);
    const int m0 = (nb >> 2) * 128;
    const int n0 = (nb & 3) * 128;

    const int tid = threadIdx.x, lane = tid & 63, w = tid >> 6;
    const int l15 = lane & 15, rg = lane >> 4;
    const int wm = w >> 1, wn = w & 1;

    auto stage = [&](int b, int kb) {
#pragma unroll
        for (int i = 0; i < 4; i++) {
            int ch = i * 256 + tid;
            int r = ch >> 3, c = ch & 7;
            int co = ((c ^ (r & 7)) << 3);
            gl16(xn + (size_t)(m0 + r) * DD + kb + co,
                 &sA[b][0] + (i * 256 + (w << 6)) * 8);
            gl16(Wg + (size_t)(n0 + r) * DD + kb + co,
                 &sB[b][0] + (i * 256 + (w << 6)) * 8);
        }
    };

    f32x4 acc[4][4];
#pragma unroll
    for (int i = 0; i < 4; i++)
#pragma unroll
        for (int j = 0; j < 4; j++) acc[i][j] = (f32x4){0.f, 0.f, 0.f, 0.f};

    stage(0, 0);
    __syncthreads();

    for (int t = 0; t < 32; t++) {
        int cur = t & 1, nxt = cur ^ 1;
        if (t < 31) stage(nxt, (t + 1) * 64);
#pragma unroll
        for (int kk = 0; kk < 2; kk++) {
            int kc = kk * 4 + rg;
            short8_t af[4], bf[4];
#pragma unroll
            for (int mi = 0; mi < 4; mi++) {
                int rr = wm * 64 + mi * 16 + l15;
                af[mi] = *(const short8_t*)(&sA[cur][0] + rr * 64 + ((kc ^ (rr & 7)) << 3));
            }
#pragma unroll
            for (int ni = 0; ni < 4; ni++) {
                int rr = wn * 64 + ni * 16 + l15;
                bf[ni] = *(const short8_t*)(&sB[cur][0] + rr * 64 + ((kc ^ (rr & 7)) << 3));
            }
#pragma unroll
            for (int mi = 0; mi < 4; mi++)
#pragma unroll
                for (int ni = 0; ni < 4; ni++)
                    acc[mi][ni] = __builtin_amdgcn_mfma_f32_16x16x32_bf16(
                        af[mi], bf[ni], acc[mi][ni], 0, 0, 0);
        }
        __syncthreads();
    }

    // epilogue: + c2 + bd, relu -> hid bf16
#pragma unroll
    for (int ni = 0; ni < 4; ni++) {
        int h = n0 + wn * 64 + ni * 16 + l15;
        float C = c2[h] + bd[h];
#pragma unroll
        for (int mi = 0; mi < 4; mi++) {
#pragma unroll
            for (int j = 0; j < 4; j++) {
                int rowL = wm * 64 + mi * 16 + rg * 4 + j;
                float v = acc[mi][ni][j] + C;
                v = v > 0.f ? v : 0.f;
                hid[(size_t)(m0 + rowL) * HH + h] = f2bf(v);
            }
        }
    }
}

// ---- k_up: out = xn*sd + mu + bu + hid @ Wu^T, 128x128 tile, BK=64, dbuf ----
__global__ __launch_bounds__(256, 2) void k_up(
    const short* __restrict__ xn, const short* __restrict__ hid,
    const short* __restrict__ Wub, const float* __restrict__ bu,
    const float* __restrict__ muv, const float* __restrict__ sdv,
    float* __restrict__ out)
{
    __shared__ __align__(16) short sA[2][128 * 64];  // 32 KB
    __shared__ __align__(16) short sB[2][128 * 64];  // 32 KB
    __shared__ float s_mu[128], s_sd[128];           // 1 KB

    // bijective XCD swizzle (nwg=2048), n fastest within each XCD chunk
    int bid = blockIdx.x;
    int nb = (bid & 7) * 256 + (bid >> 3);
    const int m0 = (nb >> 4) * 128;
    const int n0 = (nb & 15) * 128;

    const int tid = threadIdx.x, lane = tid & 63, w = tid >> 6;
    const int l15 = lane & 15, rg = lane >> 4;
    const int wm = w >> 1, wn = w & 1;

    auto stage = [&](int b, int kb) {
#pragma unroll
        for (int i = 0; i < 4; i++) {
            int ch = i * 256 + tid;
            int r = ch >> 3, c = ch & 7;
            int co = ((c ^ (r & 7)) << 3);
            gl16(hid + (size_t)(m0 + r) * HH + kb + co,
                 &sA[b][0] + (i * 256 + (w << 6)) * 8);
            gl16(Wub + (size_t)(n0 + r) * HH + kb + co,
                 &sB[b][0] + (i * 256 + (w << 6)) * 8);
        }
    };

    f32x4 acc[4][4];
#pragma unroll
    for (int i = 0; i < 4; i++)
#pragma unroll
        for (int j = 0; j < 4; j++) acc[i][j] = (f32x4){0.f, 0.f, 0.f, 0.f};

    stage(0, 0);
    if (tid < 128) { s_mu[tid] = muv[m0 + tid]; s_sd[tid] = sdv[m0 + tid]; }
    __syncthreads();

    for (int t = 0; t < 8; t++) {
        int cur = t & 1, nxt = cur ^ 1;
        if (t < 7) stage(nxt, (t + 1) * 64);
#pragma unroll
        for (int kk = 0; kk < 2; kk++) {
            int kc = kk * 4 + rg;
            short8_t af[4], bf[4];
#pragma unroll
            for (int mi = 0; mi < 4; mi++) {
                int rr = wm * 64 + mi * 16 + l15;
                af[mi] = *(const short8_t*)(&sA[cur][0] + rr * 64 + ((kc ^ (rr & 7)) << 3));
            }
#pragma unroll
            for (int ni = 0; ni < 4; ni++) {
                int rr = wn * 64 + ni * 16 + l15;
                bf[ni] = *(const short8_t*)(&sB[cur][0] + rr * 64 + ((kc ^ (rr & 7)) << 3));
            }
#pragma unroll
            for (int mi = 0; mi < 4; mi++)
#pragma unroll
                for (int ni = 0; ni < 4; ni++)
                    acc[mi][ni] = __builtin_amdgcn_mfma_f32_16x16x32_bf16(
                        af[mi], bf[ni], acc[mi][ni], 0, 0, 0);
        }
        __syncthreads();
    }

    // epilogue: out = (xn*sd + mu) + bu + acc   (residual from L3-hot xn)
#pragma unroll
    for (int ni = 0; ni < 4; ni++) {
        int d = n0 + wn * 64 + ni * 16 + l15;
        float B = bu[d];
#pragma unroll
        for (int mi = 0; mi < 4; mi++) {
#pragma unroll
            for (int j = 0; j < 4; j++) {
                int rowL = wm * 64 + mi * 16 + rg * 4 + j;
                size_t idx = (size_t)(m0 + rowL) * DD + d;
                float xv = bf2f(((const unsigned short*)xn)[idx]);
                out[idx] = fmaf(xv, s_sd[rowL], s_mu[rowL]) + B + acc[mi][ni][j];
            }
        }
    }
}

extern "C" void kernel_launch(void* const* d_in, const int* in_sizes, int n_in,
                              void* d_out, int out_size, void* d_ws, size_t ws_size,
                              hipStream_t stream) {
    const float* x     = (const float*)d_in[0];
    const float* gamma = (const float*)d_in[1];
    const float* beta  = (const float*)d_in[2];
    const float* Wd_f  = (const float*)d_in[3];  // [H, D]
    const float* bd    = (const float*)d_in[4];
    const float* Wu_f  = (const float*)d_in[5];  // [D, H]
    const float* bu    = (const float*)d_in[6];

    short* Wg  = (short*)d_ws;                     // 2 MB bf16 [H][D] (Wd*gamma)
    short* Wub = Wg + (size_t)HH * DD;             // 2 MB bf16 [D][H]
    float* c2  = (float*)(Wub + (size_t)DD * HH);  // 2 KB
    float* muv = c2 + HH;                          // 64 KB
    float* sdv = muv + NTOK;                       // 64 KB
    short* hid = (short*)(sdv + NTOK);             // 16 MB bf16 [NTOK][H]
    short* xn  = hid + (size_t)NTOK * HH;          // 64 MB bf16 [NTOK][D]

    k_prep<<<384 + NTOK, 256, 0, stream>>>(Wd_f, gamma, beta, Wu_f, x,
                                           Wg, Wub, c2, xn, muv, sdv);
    k_down<<<(NTOK / 128) * (HH / 128), 256, 0, stream>>>(xn, Wg, c2, bd, hid);
    k_up<<<(NTOK / 128) * (DD / 128), 256, 0, stream>>>(xn, hid, Wub, bu,
                                                        muv, sdv, (float*)d_out);
}